// Round 10
// baseline (548.715 us; speedup 1.0000x reference)
//
#include <hip/hip_runtime.h>
#include <math.h>

// CapsLayer dynamic routing, MI355X fp32.
// x: [64, 2048, 8]  W: [2048, 32, 8, 16]  out: [64, 32, 16]
// Never materialize u_hat (256 MB); recompute per routing pass.
// R12: eliminate the P partial matrix. Route blocks atomicAdd their
// c-weighted partials (4 KB each) directly into s[b,n,e] (128 KB, one slice
// per pass). Kills per-pass 32 MB P-write + 32 MB P-read + the 512-block
// reduce; squash becomes a 512-block 128 KB kernel. Device-scope atomicAdd
// resolves at the shared memory-side point (cross-XCD safe, m20); cross-
// kernel visibility via dispatch-boundary cache maintenance (already relied
// on for v0/vs). Route body = R5's proven one (47.6us, VGPR 36, no spill):
//   - R3/R4/R6/R8: every attempt to batch W in registers (unroll, ping-pong,
//     launch_bounds(256,8)) spilled to scratch -> unroll-1 guard is law.
//   - R9/R10 (LDS staging): same ~50us wall, more complexity. R11 (1-wave
//     blocks): 131us, uncoalesced W (32 lines/instr). 256-thr (eq,bh,n)
//     lane map is the coalescing-optimal layout; keep it.
// Tripwires: route WRITE_SIZE < 4 MB (P gone), dur <= 55us (atomics ok),
// FETCH ~36 MB (no spill), absmax <= 1e-3 (i-sum reorder noise ~1e-6).

#define B_TOT 64
#define I_TOT 2048
#define D_IN  8
#define NC    32
#define EV    16
#define OD    (NC*EV)      // 512 outputs per b
#define BC    8            // batch rows per block
#define NBC   (B_TOT/BC)   // 8 b-chunks
#define ICH   8            // i's per block
#define NIC   (I_TOT/ICH)  // 256 i-chunks
#define S_ELEMS (B_TOT*OD) // 32768 floats = 128 KB per s-slice

__device__ __forceinline__ void fma4(float4& acc, float a, const float4& w) {
    acc.x = fmaf(a, w.x, acc.x);
    acc.y = fmaf(a, w.y, acc.y);
    acc.z = fmaf(a, w.z, acc.z);
    acc.w = fmaf(a, w.w, acc.w);
}

// zero the 3 s-slices (contiguous, 3*32768 floats)
__global__ void zero_s(float* __restrict__ s)
{
    s[(size_t)blockIdx.x * 256 + threadIdx.x] = 0.f;
}

// MODE 0: c uniform (iter 0)              -> atomicAdd partials into s
// MODE 1: c = softmax_n(u . vin)          -> atomicAdd partials into s
//         (iter 2 uses vin = v0+v1: dot is linear, so no logit carry needed)
template <int MODE>
__global__ __launch_bounds__(256, 4)
void route_pass(const float* __restrict__ x, const float* __restrict__ W,
                float* __restrict__ s, const float* __restrict__ vin)
{
    __shared__ __align__(16) float xl[BC * ICH * D_IN];   // 2 KB
    __shared__ float wsum[2][4][BC];                      // 256 B (ii-dbuf)

    const int t  = threadIdx.x;
    // XCD swizzle: blk%8 == ic%8 (NIC = 256 ≡ 0 mod 8), so the 8 bc-siblings
    // of an ic (which share W[i0..i0+7]) land on the same XCD's L2.
    const int ic = blockIdx.x & (NIC - 1);   // 0..255
    const int bc = blockIdx.x >> 8;          // 0..7
    const int b0 = bc * BC;
    const int i0 = ic * ICH;
    const int eq = t & 3;          // e quarter (4 e's)
    const int bh = (t >> 2) & 1;   // b half (4 b's each)
    const int n  = t >> 3;         // capsule 0..31
    const int w  = t >> 6;         // wave 0..3

    // ---- stage x[b0..b0+7][i0..i0+7][0..7] once (2 KB) ----
    if (t < 128) {
        const int row = t >> 4, f = (t & 15) * 4;
        *(float4*)&xl[row * (ICH * D_IN) + f] =
            *(const float4*)&x[((size_t)(b0 + row) * I_TOT + i0) * D_IN + f];
    }

    // ---- v fragments in registers (loaded once; L2-hot, tiny) ----
    float4 vr[4];
    if (MODE == 1) {
        #pragma unroll
        for (int q = 0; q < 4; ++q)
            vr[q] = *(const float4*)&vin[(size_t)(b0 + bh * 4 + q) * OD + n * EV + eq * 4];
    }
    __syncthreads();

    float4 sacc[4];
    #pragma unroll
    for (int q = 0; q < 4; ++q) sacc[q] = make_float4(0.f, 0.f, 0.f, 0.f);

    const float* Wt = &W[(size_t)i0 * 4096 + n * 128 + eq * 4];

    // unroll 1 is load-bearing: with ICH=8 the unroller otherwise flattens
    // this loop and hoists 64 float4 W loads -> 256 VGPRs -> scratch spill
    // (R3/R4: 1.1 GB/pass HBM, VALUBusy 2.8%). Keep per-iter live set small;
    // latency is hidden by TLP, not ILP (R6: ILP re-spilled).
    #pragma unroll 1
    for (int ii = 0; ii < ICH; ++ii) {
        // ---- this thread's W fragment straight from global (64B-coalesced) ----
        float4 wr[8];
        #pragma unroll
        for (int d = 0; d < 8; ++d)
            wr[d] = *(const float4*)&Wt[ii * 4096 + d * 16];

        // ---- u[bl][eq*4..+3] for 4 batch rows ----
        float4 u[4];
        #pragma unroll
        for (int q = 0; q < 4; ++q) {
            const int bl = bh * 4 + q;
            float4 xa = *(float4*)&xl[bl * (ICH * D_IN) + ii * 8];
            float4 xb = *(float4*)&xl[bl * (ICH * D_IN) + ii * 8 + 4];
            float4 uu = make_float4(0.f, 0.f, 0.f, 0.f);
            fma4(uu, xa.x, wr[0]); fma4(uu, xa.y, wr[1]);
            fma4(uu, xa.z, wr[2]); fma4(uu, xa.w, wr[3]);
            fma4(uu, xb.x, wr[4]); fma4(uu, xb.y, wr[5]);
            fma4(uu, xb.z, wr[6]); fma4(uu, xb.w, wr[7]);
            u[q] = uu;
        }

        if (MODE == 0) {
            #pragma unroll
            for (int q = 0; q < 4; ++q) {
                sacc[q].x += u[q].x; sacc[q].y += u[q].y;
                sacc[q].z += u[q].z; sacc[q].w += u[q].w;
            }
            // no barrier: xl is read-only, no LDS communication
        } else {
            // ---- a[bl] = dot(u, v) over e: 4 in-thread + shfl over eq bits ----
            float a[4];
            #pragma unroll
            for (int q = 0; q < 4; ++q) {
                float ap = u[q].x * vr[q].x + u[q].y * vr[q].y
                         + u[q].z * vr[q].z + u[q].w * vr[q].w;
                ap += __shfl_xor(ap, 1, 64);
                ap += __shfl_xor(ap, 2, 64);
                a[q] = ap;
            }
            // ---- softmax over n: exp, in-wave partial over this wave's 8 n's ----
            float e[4], p[4];
            #pragma unroll
            for (int q = 0; q < 4; ++q) {
                e[q] = __expf(a[q]);
                float pp = e[q];
                pp += __shfl_xor(pp, 8, 64);
                pp += __shfl_xor(pp, 16, 64);
                pp += __shfl_xor(pp, 32, 64);
                p[q] = pp;       // sum over n in this wave, for bl = bh*4+q
            }
            if (eq == 0) {
                #pragma unroll
                for (int q = 0; q < 4; ++q)
                    wsum[ii & 1][w][bh * 4 + q] = p[q];
            }
            __syncthreads();     // the ONLY barrier per i (wsum double-buffered)
            #pragma unroll
            for (int q = 0; q < 4; ++q) {
                const int bl = bh * 4 + q;
                float ssum = wsum[ii & 1][0][bl] + wsum[ii & 1][1][bl]
                           + wsum[ii & 1][2][bl] + wsum[ii & 1][3][bl];
                float c = __fdividef(e[q], ssum);
                fma4(sacc[q], c, u[q]);
            }
        }
    }

    // ---- accumulate partials directly into s[b][o] (device-scope atomics,
    //      fire-and-forget; 16 adds/thread, 4 KB per block into 128 KB) ----
    #pragma unroll
    for (int q = 0; q < 4; ++q) {
        float* sp = &s[(size_t)(b0 + bh * 4 + q) * OD + n * EV + eq * 4];
        atomicAdd(sp + 0, sacc[q].x);
        atomicAdd(sp + 1, sacc[q].y);
        atomicAdd(sp + 2, sacc[q].z);
        atomicAdd(sp + 3, sacc[q].w);
    }
}

// squash per (b, n) from the 128 KB s-slice. Grid: 64 b x 8 o-slices = 512
// one-wave blocks. Norm over e = 16 consecutive lanes.
// If addsrc != null, out = squash(...) + addsrc  (used to produce v0+v1).
__global__ __launch_bounds__(64, 8)
void squash_k(const float* __restrict__ s, float* __restrict__ dst,
              const float* __restrict__ addsrc, float pre)
{
    const int b = blockIdx.x >> 3;
    const int o = (blockIdx.x & 7) * 64 + threadIdx.x;
    float v = s[(size_t)b * OD + o] * pre;
    float q2 = v * v;
    q2 += __shfl_xor(q2, 1, 64);
    q2 += __shfl_xor(q2, 2, 64);
    q2 += __shfl_xor(q2, 4, 64);
    q2 += __shfl_xor(q2, 8, 64);
    float sc = q2 / ((1.0f + q2) * sqrtf(q2));
    float outv = v * sc;
    if (addsrc) outv += addsrc[(size_t)b * OD + o];
    dst[(size_t)b * OD + o] = outv;
}

extern "C" void kernel_launch(void* const* d_in, const int* in_sizes, int n_in,
                              void* d_out, int out_size, void* d_ws, size_t ws_size,
                              hipStream_t stream) {
    const float* x = (const float*)d_in[0];
    const float* W = (const float*)d_in[1];
    float* out = (float*)d_out;

    float* s0 = (float*)d_ws;            // 128 KB each, contiguous
    float* s1 = s0 + S_ELEMS;
    float* s2 = s1 + S_ELEMS;
    float* v0 = s2 + S_ELEMS;
    float* vs = v0 + S_ELEMS;            // v0 + v1

    dim3 rg(NBC * NIC), rb(256);   // 2048 blocks
    dim3 sg(B_TOT * 8), sb(64);    // 512 one-wave blocks

    // zero all three s-slices (workspace may be poisoned between iterations)
    zero_s<<<dim3(3 * S_ELEMS / 256), dim3(256), 0, stream>>>(s0);

    // iter 0: uniform c = 1/32 (applied as pre in squash)
    route_pass<0><<<rg, rb, 0, stream>>>(x, W, s0, nullptr);
    squash_k<<<sg, sb, 0, stream>>>(s0, v0, nullptr, 1.0f / 32.0f);
    // iter 1: c = softmax(u.v0)
    route_pass<1><<<rg, rb, 0, stream>>>(x, W, s1, v0);
    // vs = v0 + v1  (iter-2 logits: u.v0 + u.v1 = u.(v0+v1))
    squash_k<<<sg, sb, 0, stream>>>(s1, vs, v0, 1.0f);
    // iter 2: c = softmax(u.(v0+v1)); final
    route_pass<1><<<rg, rb, 0, stream>>>(x, W, s2, vs);
    squash_k<<<sg, sb, 0, stream>>>(s2, out, nullptr, 1.0f);
}

// Round 11
// 190.225 us; speedup vs baseline: 2.8846x; 2.8846x over previous
//
#include <hip/hip_runtime.h>
#include <math.h>

// CapsLayer dynamic routing, MI355X fp32.
// x: [64, 2048, 8]  W: [2048, 32, 8, 16]  out: [64, 32, 16]
// Never materialize u_hat (256 MB); recompute per routing pass.
// R13: (a) pass-0 as GEMM (no softmax -> no per-i u needed: fold W fragment
// into 8 batch rows directly, BC=16, half the W L2 traffic, 2x compute per
// load); (b) reduce as 2048-block stage + 4-way atomicAdd into s[b,o]
// (R12 proved 256-way line fan-in serializes; 4-way is safe) + tiny squash.
// route<1> (MODE1) body = R5's proven 47.6us kernel, untouched.
// Spill law (R3/R4/R6/R8): W must not be batched in registers across ii;
// #pragma unroll 1 on the ii loop is load-bearing everywhere.
// Tripwires: FETCH ~36 MB/route (>100 = spill); route0 VGPR <= 110;
// reduce atomics fan-in 4 only; absmax <= 1e-3.

#define B_TOT 64
#define I_TOT 2048
#define D_IN  8
#define NC    32
#define EV    16
#define OD    (NC*EV)      // 512 outputs per b
#define BC    8            // batch rows per block (MODE1)
#define NBC   (B_TOT/BC)   // 8 b-chunks
#define BC0   16           // batch rows per block (pass-0 GEMM)
#define NBC0  (B_TOT/BC0)  // 4 b-chunks
#define ICH   8            // i's per block
#define NIC   (I_TOT/ICH)  // 256 i-chunks
#define S_ELEMS (B_TOT*OD) // 32768 floats = 128 KB per s-slice

__device__ __forceinline__ void fma4(float4& acc, float a, const float4& w) {
    acc.x = fmaf(a, w.x, acc.x);
    acc.y = fmaf(a, w.y, acc.y);
    acc.z = fmaf(a, w.z, acc.z);
    acc.w = fmaf(a, w.w, acc.w);
}

// zero the 3 s-slices (contiguous, 3*32768 floats)
__global__ void zero_s(float* __restrict__ s)
{
    s[(size_t)blockIdx.x * 256 + threadIdx.x] = 0.f;
}

// ---- pass 0: c uniform. s0 = sum_i x[b,i,:] @ W[i] — a GEMM, no per-i u.
// BC0=16 rows/block: thread (eq,bh,n) folds wr[8] into 8 b-rows directly.
__global__ __launch_bounds__(256, 4)
void route0(const float* __restrict__ x, const float* __restrict__ W,
            float* __restrict__ P)
{
    __shared__ __align__(16) float xl[BC0 * ICH * D_IN];  // 4 KB

    const int t  = threadIdx.x;
    const int ic = blockIdx.x & (NIC - 1);   // 0..255 (blk%8==ic%8: XCD swz)
    const int bc = blockIdx.x >> 8;          // 0..3
    const int b0 = bc * BC0;
    const int i0 = ic * ICH;
    const int eq = t & 3;
    const int bh = (t >> 2) & 1;
    const int n  = t >> 3;

    // stage x[b0..b0+15][i0..i0+7][0..7] (4 KB): 256 float4, one per thread
    {
        const int row = t >> 4, f = (t & 15) * 4;
        *(float4*)&xl[row * (ICH * D_IN) + f] =
            *(const float4*)&x[((size_t)(b0 + row) * I_TOT + i0) * D_IN + f];
    }
    __syncthreads();

    float4 sacc[8];
    #pragma unroll
    for (int q = 0; q < 8; ++q) sacc[q] = make_float4(0.f, 0.f, 0.f, 0.f);

    const float* Wt = &W[(size_t)i0 * 4096 + n * 128 + eq * 4];

    // unroll 1 is load-bearing (spill law)
    #pragma unroll 1
    for (int ii = 0; ii < ICH; ++ii) {
        float4 wr[8];
        #pragma unroll
        for (int d = 0; d < 8; ++d)
            wr[d] = *(const float4*)&Wt[ii * 4096 + d * 16];

        #pragma unroll
        for (int q = 0; q < 8; ++q) {
            const int bl = bh * 8 + q;
            float4 xa = *(float4*)&xl[bl * (ICH * D_IN) + ii * 8];
            float4 xb = *(float4*)&xl[bl * (ICH * D_IN) + ii * 8 + 4];
            fma4(sacc[q], xa.x, wr[0]); fma4(sacc[q], xa.y, wr[1]);
            fma4(sacc[q], xa.z, wr[2]); fma4(sacc[q], xa.w, wr[3]);
            fma4(sacc[q], xb.x, wr[4]); fma4(sacc[q], xb.y, wr[5]);
            fma4(sacc[q], xb.z, wr[6]); fma4(sacc[q], xb.w, wr[7]);
        }
    }

    #pragma unroll
    for (int q = 0; q < 8; ++q)
        *(float4*)&P[((size_t)ic * B_TOT + b0 + bh * 8 + q) * OD + n * EV + eq * 4] = sacc[q];
}

// ---- passes 1/2: c = softmax_n(u . vin). R5's proven body, untouched.
// (iter 2 uses vin = v0+v1: dot is linear, so no logit carry needed)
__global__ __launch_bounds__(256, 4)
void route1(const float* __restrict__ x, const float* __restrict__ W,
            float* __restrict__ P, const float* __restrict__ vin)
{
    __shared__ __align__(16) float xl[BC * ICH * D_IN];   // 2 KB
    __shared__ float wsum[2][4][BC];                      // 256 B (ii-dbuf)

    const int t  = threadIdx.x;
    const int ic = blockIdx.x & (NIC - 1);   // 0..255
    const int bc = blockIdx.x >> 8;          // 0..7
    const int b0 = bc * BC;
    const int i0 = ic * ICH;
    const int eq = t & 3;          // e quarter (4 e's)
    const int bh = (t >> 2) & 1;   // b half (4 b's each)
    const int n  = t >> 3;         // capsule 0..31
    const int w  = t >> 6;         // wave 0..3

    if (t < 128) {
        const int row = t >> 4, f = (t & 15) * 4;
        *(float4*)&xl[row * (ICH * D_IN) + f] =
            *(const float4*)&x[((size_t)(b0 + row) * I_TOT + i0) * D_IN + f];
    }

    float4 vr[4];
    #pragma unroll
    for (int q = 0; q < 4; ++q)
        vr[q] = *(const float4*)&vin[(size_t)(b0 + bh * 4 + q) * OD + n * EV + eq * 4];
    __syncthreads();

    float4 sacc[4];
    #pragma unroll
    for (int q = 0; q < 4; ++q) sacc[q] = make_float4(0.f, 0.f, 0.f, 0.f);

    const float* Wt = &W[(size_t)i0 * 4096 + n * 128 + eq * 4];

    // unroll 1 is load-bearing (spill law)
    #pragma unroll 1
    for (int ii = 0; ii < ICH; ++ii) {
        float4 wr[8];
        #pragma unroll
        for (int d = 0; d < 8; ++d)
            wr[d] = *(const float4*)&Wt[ii * 4096 + d * 16];

        float4 u[4];
        #pragma unroll
        for (int q = 0; q < 4; ++q) {
            const int bl = bh * 4 + q;
            float4 xa = *(float4*)&xl[bl * (ICH * D_IN) + ii * 8];
            float4 xb = *(float4*)&xl[bl * (ICH * D_IN) + ii * 8 + 4];
            float4 uu = make_float4(0.f, 0.f, 0.f, 0.f);
            fma4(uu, xa.x, wr[0]); fma4(uu, xa.y, wr[1]);
            fma4(uu, xa.z, wr[2]); fma4(uu, xa.w, wr[3]);
            fma4(uu, xb.x, wr[4]); fma4(uu, xb.y, wr[5]);
            fma4(uu, xb.z, wr[6]); fma4(uu, xb.w, wr[7]);
            u[q] = uu;
        }

        float a[4];
        #pragma unroll
        for (int q = 0; q < 4; ++q) {
            float ap = u[q].x * vr[q].x + u[q].y * vr[q].y
                     + u[q].z * vr[q].z + u[q].w * vr[q].w;
            ap += __shfl_xor(ap, 1, 64);
            ap += __shfl_xor(ap, 2, 64);
            a[q] = ap;
        }
        float e[4], p[4];
        #pragma unroll
        for (int q = 0; q < 4; ++q) {
            e[q] = __expf(a[q]);
            float pp = e[q];
            pp += __shfl_xor(pp, 8, 64);
            pp += __shfl_xor(pp, 16, 64);
            pp += __shfl_xor(pp, 32, 64);
            p[q] = pp;
        }
        if (eq == 0) {
            #pragma unroll
            for (int q = 0; q < 4; ++q)
                wsum[ii & 1][w][bh * 4 + q] = p[q];
        }
        __syncthreads();
        #pragma unroll
        for (int q = 0; q < 4; ++q) {
            const int bl = bh * 4 + q;
            float s = wsum[ii & 1][0][bl] + wsum[ii & 1][1][bl]
                    + wsum[ii & 1][2][bl] + wsum[ii & 1][3][bl];
            float c = e[q] / s;
            fma4(sacc[q], c, u[q]);
        }
    }

    #pragma unroll
    for (int q = 0; q < 4; ++q)
        *(float4*)&P[((size_t)ic * B_TOT + b0 + bh * 4 + q) * OD + n * EV + eq * 4] = sacc[q];
}

// ---- reduce stage: 2048 blocks (b x oq x icq); each sums 64 ics for 64
// outputs, LDS-combines 4 sub-sums, and atomicAdds 64 floats into s[b,o].
// Fan-in per s cell = 4 (icq) — R12's 256-way was the serializer; 4 is safe.
__global__ __launch_bounds__(256, 4)
void reduce_p(const float* __restrict__ P, float* __restrict__ s)
{
    __shared__ float red[256];
    const int b   = blockIdx.x >> 5;              // 0..63
    const int oq  = (blockIdx.x >> 2) & 7;        // 0..7
    const int icq = blockIdx.x & 3;               // 0..3
    const int t   = threadIdx.x;
    const int o   = oq * 64 + (t & 63);
    const int sub = t >> 6;                       // 0..3
    const size_t stride = (size_t)B_TOT * OD;

    float acc = 0.f;
    size_t base = ((size_t)(icq * 64 + sub * 16) * B_TOT + b) * OD + o;
    #pragma unroll
    for (int k = 0; k < 16; ++k) acc += P[base + (size_t)k * stride];
    red[t] = acc;
    __syncthreads();
    if (t < 64) {
        float v = red[t] + red[t + 64] + red[t + 128] + red[t + 192];
        atomicAdd(&s[(size_t)b * OD + o], v);
    }
}

// squash per (b, n) from the 128 KB s-slice. 512 one-wave blocks.
// If addsrc != null, out = squash(...) + addsrc  (used to produce v0+v1).
__global__ __launch_bounds__(64, 8)
void squash_k(const float* __restrict__ s, float* __restrict__ dst,
              const float* __restrict__ addsrc, float pre)
{
    const int b = blockIdx.x >> 3;
    const int o = (blockIdx.x & 7) * 64 + threadIdx.x;
    float v = s[(size_t)b * OD + o] * pre;
    float q2 = v * v;
    q2 += __shfl_xor(q2, 1, 64);
    q2 += __shfl_xor(q2, 2, 64);
    q2 += __shfl_xor(q2, 4, 64);
    q2 += __shfl_xor(q2, 8, 64);
    float sc = q2 / ((1.0f + q2) * sqrtf(q2));
    float outv = v * sc;
    if (addsrc) outv += addsrc[(size_t)b * OD + o];
    dst[(size_t)b * OD + o] = outv;
}

extern "C" void kernel_launch(void* const* d_in, const int* in_sizes, int n_in,
                              void* d_out, int out_size, void* d_ws, size_t ws_size,
                              hipStream_t stream) {
    const float* x = (const float*)d_in[0];
    const float* W = (const float*)d_in[1];
    float* out = (float*)d_out;

    char* ws = (char*)d_ws;
    float* P  = (float*)ws;                               // 32 MB
    float* s0 = (float*)(ws + (size_t)32 * 1024 * 1024);  // 128 KB each
    float* s1 = s0 + S_ELEMS;
    float* s2 = s1 + S_ELEMS;
    float* v0 = s2 + S_ELEMS;
    float* vs = v0 + S_ELEMS;                             // v0 + v1

    dim3 r0g(NBC0 * NIC), r1g(NBC * NIC), rb(256);  // 1024 / 2048 blocks
    dim3 dg(B_TOT * 8 * 4), db(256);                // 2048 reduce blocks
    dim3 sg(B_TOT * 8), sb(64);                     // 512 squash blocks

    // zero all three s-slices (atomic accumulation targets)
    zero_s<<<dim3(3 * S_ELEMS / 256), dim3(256), 0, stream>>>(s0);

    // iter 0: uniform c = 1/32 (applied as pre in squash) — GEMM form
    route0<<<r0g, rb, 0, stream>>>(x, W, P);
    reduce_p<<<dg, db, 0, stream>>>(P, s0);
    squash_k<<<sg, sb, 0, stream>>>(s0, v0, nullptr, 1.0f / 32.0f);
    // iter 1: c = softmax(u.v0)
    route1<<<r1g, rb, 0, stream>>>(x, W, P, v0);
    reduce_p<<<dg, db, 0, stream>>>(P, s1);
    // vs = v0 + v1  (iter-2 logits: u.v0 + u.v1 = u.(v0+v1))
    squash_k<<<sg, sb, 0, stream>>>(s1, vs, v0, 1.0f);
    // iter 2: c = softmax(u.(v0+v1)); final
    route1<<<r1g, rb, 0, stream>>>(x, W, P, vs);
    reduce_p<<<dg, db, 0, stream>>>(P, s2);
    squash_k<<<sg, sb, 0, stream>>>(s2, out, nullptr, 1.0f);
}